// Round 1
// 4627.903 us; speedup vs baseline: 1.1847x; 1.1847x over previous
//
#include <hip/hip_runtime.h>

#define ZB 202
#define YX 65536
#define NTOT ((size_t)ZB * YX)

#define TILE 16            // pixels per LDS tile (1 KB/step: 64 lanes x 16B)
#define NT (YX / TILE)     // 4096 tiles
#define NBUF 4             // LDS ring buffers: read t while t+1..t+3 stage

__device__ __forceinline__ constexpr float kMU() { return 0.0009765625f; }  // 2^-10
#define MINV (-32768.0f)
#define MAXV (32767.0f)

// global->LDS direct DMA: no VGPR destinations, so in-flight depth is not
// bounded by register allocation (the round-2 failure: 32x float4 prefetch
// needed 128 VGPRs, rocprof showed only 96 allocated -> spilled/sunk loads
// -> 196 cyc/step latency-bound loop).
#define GL_LDS16(g, l)                                                    \
    __builtin_amdgcn_global_load_lds(                                     \
        (const __attribute__((address_space(1))) void*)(g),               \
        (__attribute__((address_space(3))) void*)(l), 16, 0, 0)

// ---------------------------------------------------------------------------
// Phase A: pack tmp4[t][z] = {img[z-3], img[z-2], img[z-1], img[z]} at pixel t.
// LDS tile: 64 z x 64 t (+3 z halo). Reads coalesced along t, writes 1KB
// contiguous float4 runs along z.  (unchanged, verified)
// ---------------------------------------------------------------------------
__global__ __launch_bounds__(256) void pack_kernel(const float* __restrict__ img,
                                                   float4* __restrict__ tmp4) {
    __shared__ float lds[67 * 65];  // rows = img z0-3 .. z0+63, pitch 65 (bank-conflict pad)
    const int t0 = blockIdx.x * 64;
    const int z0 = blockIdx.y * 64;
    const int tid = threadIdx.x;
    const int c = tid & 63;
    const int r0 = tid >> 6;

    for (int k = 0; k < 17; ++k) {
        int r = r0 + (k << 2);
        if (r < 67) {
            int gz = z0 - 3 + r;
            float v = 0.0f;
            if (gz >= 0 && gz < ZB) v = img[(size_t)gz * YX + t0 + c];
            lds[r * 65 + c] = v;
        }
    }
    __syncthreads();

    const int zl = tid & 63;
    const int tsub = tid >> 6;
    const int z = z0 + zl;
    if (z >= ZB) return;
    for (int k = 0; k < 16; ++k) {
        int tl = tsub * 16 + k;
        float4 v;
        v.x = lds[(zl + 0) * 65 + tl];  // img[z-3] = n2
        v.y = lds[(zl + 1) * 65 + tl];  // img[z-2] = n1
        v.z = lds[(zl + 2) * 65 + tl];  // img[z-1] = n0
        v.w = lds[(zl + 3) * 65 + tl];  // img[z]   = s
        tmp4[(size_t)(t0 + tl) * ZB + z] = v;
    }
}

// ---------------------------------------------------------------------------
// Phase B: sequential sign-LMS scan. One lane per band; 4 waves total.
//
// Latency cover via LDS pipeline (NOT a register buffer):
//   - 4 ring buffers of TILE=16 steps (64 KB LDS total).
//   - stage tile t+3 with 16x global_load_lds (48 loads in flight steady
//     state; issued ~3*16*~40 = ~1900 cyc before use >= ~900 cyc HBM lat).
//   - per-tile boundary: s_waitcnt vmcnt(48) -- counted, never drained to 0
//     in the main loop; tail peels 32/16/0.
//   - inner loop: 1 ds_read_b128 per step (contiguous 16B/lane = conflict
//     free), compiler pipelines with counted lgkmcnt.
//
// Recurrence kept bit-exact vs the previously-verified kernel:
//  - d uses the same 3-mul + left-to-right 2-add order.
//  - sign(s - clip(d)) == sign(s - d) because |s| < 32767 always.
//  - w' = fma(+-MU, v, w) bit-identical to w + (MU*sign)*v (MU = 2^-10 exact).
//  - stores UNCLIPPED d; finalize applies the clamp.
// ---------------------------------------------------------------------------
__global__ __launch_bounds__(64, 1) void scan_kernel(const float4* __restrict__ tmp4,
                                                     const float* __restrict__ w0g,
                                                     float* __restrict__ dT) {
    __shared__ float4 lds[NBUF * TILE * 64];  // 64 KB ring

    const int lane = threadIdx.x;
    const int z = blockIdx.x * 64 + lane;
    if (z >= ZB) return;  // single wave per block: no barriers, early-out safe

    float w0 = w0g[z * 3 + 0];
    float w1 = w0g[z * 3 + 1];
    float w2 = w0g[z * 3 + 2];

    const float4* gsrc = tmp4 + z;  // per-lane: 64 lanes -> contiguous 1KB per step
    float* outp = dT + z;

    auto stage = [&](int tile) {
        const float4* gp = gsrc + (size_t)tile * (TILE * ZB);
        float4* lp = &lds[(tile & (NBUF - 1)) * (TILE * 64)];  // wave-uniform base
#pragma unroll
        for (int k = 0; k < TILE; ++k) {
            GL_LDS16(gp + (size_t)k * ZB, lp + k * 64);
        }
    };

    // prologue: 3 tiles in flight
    stage(0);
    stage(1);
    stage(2);

    for (int t = 0; t < NT; ++t) {
        if (t + 3 < NT) stage(t + 3);

        // ensure tile t landed; keep the younger tiles' loads in flight
        if (t + 3 < NT)      asm volatile("s_waitcnt vmcnt(48)" ::: "memory");
        else if (t + 2 < NT) asm volatile("s_waitcnt vmcnt(32)" ::: "memory");
        else if (t + 1 < NT) asm volatile("s_waitcnt vmcnt(16)" ::: "memory");
        else                 asm volatile("s_waitcnt vmcnt(0)"  ::: "memory");

        const float4* lbuf = &lds[(t & (NBUF - 1)) * (TILE * 64) + lane];
        const size_t obase = (size_t)t * TILE * ZB;
#pragma unroll
        for (int i = 0; i < TILE; ++i) {
            const float4 v = lbuf[(size_t)i * 64];  // ds_read_b128
            // d: identical op order to the validated kernel
            float d = __fadd_rn(__fadd_rn(__fmul_rn(w0, v.z), __fmul_rn(w1, v.y)),
                                __fmul_rn(w2, v.x));
            // sg = MU * sign(s - clip(d)) ; clip dropped from the chain (see above)
            float sg = (v.w > d) ? kMU() : ((v.w < d) ? -kMU() : 0.0f);
            w0 = __builtin_fmaf(sg, v.z, w0);
            w1 = __builtin_fmaf(sg, v.y, w1);
            w2 = __builtin_fmaf(sg, v.x, w2);
            outp[obase + (size_t)i * ZB] = d;
        }
    }
}

// ---------------------------------------------------------------------------
// Phase C: elementwise outputs from dT + image. LDS-transposes a 64-pixel
// tile of dT so every global read/write is coalesced. Applies the clamp
// that scan deferred. (unchanged, verified)
// ---------------------------------------------------------------------------
__global__ __launch_bounds__(256) void finalize_kernel(const float* __restrict__ img,
                                                       const float* __restrict__ dT,
                                                       float* __restrict__ out) {
    __shared__ float lds[64 * ZB];  // 51.7 KB
    const int t0 = blockIdx.x * 64;
    const float* src = dT + (size_t)t0 * ZB;
    for (int i = threadIdx.x; i < 64 * ZB; i += 256) lds[i] = src[i];
    __syncthreads();

    for (int k = 0; k < 51; ++k) {
        int e = k * 256 + threadIdx.x;
        if (e < 64 * ZB) {
            int zz = e >> 6;
            int tl = e & 63;
            float dv = lds[tl * ZB + zz];            // stride 202 -> 2-way bank alias (free)
            float pred = fminf(fmaxf(dv, MINV), MAXV);
            size_t o = (size_t)zz * YX + t0 + tl;
            float s = img[o];
            float res = __fsub_rn(s, pred);
            int q = (int)rintf(res);                  // round-half-even == jnp.round
            int m = (q >= 0) ? (2 * q) : (-2 * q - 1);
            out[o] = pred;                            // predictions
            out[NTOT + o] = res;                      // residuals
            out[2 * NTOT + o] = res;                  // quantized_residuals
            out[3 * NTOT + o] = (float)m;             // mapped_indices
            out[5 * NTOT + o] = __fadd_rn(pred, res); // reconstructed
        }
    }
}

// ---------------------------------------------------------------------------
// Phase D: sample_representatives = image (runs after finalize has read dT
// out of this region). (unchanged)
// ---------------------------------------------------------------------------
__global__ __launch_bounds__(256) void repr_kernel(const float4* __restrict__ img4,
                                                   float4* __restrict__ out4) {
    size_t n4 = NTOT / 4;
    for (size_t i = (size_t)blockIdx.x * blockDim.x + threadIdx.x; i < n4;
         i += (size_t)gridDim.x * blockDim.x)
        out4[i] = img4[i];
}

extern "C" void kernel_launch(void* const* d_in, const int* in_sizes, int n_in,
                              void* d_out, int out_size, void* d_ws, size_t ws_size,
                              hipStream_t stream) {
    const float* img = (const float*)d_in[0];
    const float* w0g = (const float*)d_in[1];
    float* out = (float*)d_out;

    // Scratch carved out of d_out (dead before the final writers touch it):
    //   tmp4 = d_out[0 .. 4N) floats  (exactly N float4s)
    //   dT   = d_out[4N .. 5N) floats (later overwritten by repr_kernel)
    float4* tmp4 = (float4*)d_out;
    float* dT = out + 4 * NTOT;

    dim3 gA(YX / 64, 4);
    pack_kernel<<<gA, 256, 0, stream>>>(img, tmp4);
    scan_kernel<<<4, 64, 0, stream>>>(tmp4, w0g, dT);
    finalize_kernel<<<YX / 64, 256, 0, stream>>>(img, dT, out);
    repr_kernel<<<4096, 256, 0, stream>>>((const float4*)img, (float4*)(out + 4 * NTOT));
}

// Round 2
// 4444.820 us; speedup vs baseline: 1.2335x; 1.0412x over previous
//
#include <hip/hip_runtime.h>

#define ZB 202
#define YX 65536
#define NTOT ((size_t)ZB * YX)

#define TILE 16            // pixels per LDS tile (1 KB/step: 64 lanes x 16B)
#define NT (YX / TILE)     // 4096 tiles
#define NBUF 4             // LDS ring buffers

__device__ __forceinline__ constexpr float kMU() { return 0.0009765625f; }  // 2^-10
#define MINV (-32768.0f)
#define MAXV (32767.0f)

// global->LDS direct DMA: no VGPR destinations for the in-flight global loads.
#define GL_LDS16(g, l)                                                    \
    __builtin_amdgcn_global_load_lds(                                     \
        (const __attribute__((address_space(1))) void*)(g),               \
        (__attribute__((address_space(3))) void*)(l), 16, 0, 0)

// ---------------------------------------------------------------------------
// Phase A: pack tmp4[t][z] = {img[z-3], img[z-2], img[z-1], img[z]} at pixel t.
// (unchanged, verified)
// ---------------------------------------------------------------------------
__global__ __launch_bounds__(256) void pack_kernel(const float* __restrict__ img,
                                                   float4* __restrict__ tmp4) {
    __shared__ float lds[67 * 65];  // rows = img z0-3 .. z0+63, pitch 65 (bank-conflict pad)
    const int t0 = blockIdx.x * 64;
    const int z0 = blockIdx.y * 64;
    const int tid = threadIdx.x;
    const int c = tid & 63;
    const int r0 = tid >> 6;

    for (int k = 0; k < 17; ++k) {
        int r = r0 + (k << 2);
        if (r < 67) {
            int gz = z0 - 3 + r;
            float v = 0.0f;
            if (gz >= 0 && gz < ZB) v = img[(size_t)gz * YX + t0 + c];
            lds[r * 65 + c] = v;
        }
    }
    __syncthreads();

    const int zl = tid & 63;
    const int tsub = tid >> 6;
    const int z = z0 + zl;
    if (z >= ZB) return;
    for (int k = 0; k < 16; ++k) {
        int tl = tsub * 16 + k;
        float4 v;
        v.x = lds[(zl + 0) * 65 + tl];  // img[z-3] = n2
        v.y = lds[(zl + 1) * 65 + tl];  // img[z-2] = n1
        v.z = lds[(zl + 2) * 65 + tl];  // img[z-1] = n0
        v.w = lds[(zl + 3) * 65 + tl];  // img[z]   = s
        tmp4[(size_t)(t0 + tl) * ZB + z] = v;
    }
}

// ---------------------------------------------------------------------------
// Phase B: sequential sign-LMS scan. One lane per band; 4 waves total.
//
// Two-level pipeline (round-1 post-mortem: ds_read latency was exposed
// per-step, 161 cyc/step, because reads sat at their uses):
//   level 1 (HBM->LDS):  global_load_lds, 3 tiles deep, counted vmcnt waits.
//     In-order vmcnt retirement (gfx9-lineage: loads AND stores share vmcnt,
//     retire in issue order) => "wait vmcnt(K)" with K = #vmem-ops issued
//     after tile X's loads guarantees tile X landed.  Steady state K=48
//     (2x16 compute stores + 2x16 younger loads); startup pair K=32/48;
//     vmcnt(0) only in the 4-tile tail.
//   level 2 (LDS->reg):  register double-buffer ra/rb.  All 16 ds_read_b128
//     of tile t+1 batch-issue BEFORE compute of tile t (sched_barrier(0)
//     pins them); their ~120cyc latency hides under ~400cyc of compute.
//     2x-unrolled pair loop keeps every array index compile-time constant
//     (runtime-indexed ext_vector arrays go to scratch).
//
// Recurrence kept bit-exact vs the verified kernel:
//  - d uses the same 3-mul + left-to-right 2-add order.
//  - sign(s - clip(d)) == sign(s - d) because |s| < 32767 always.
//  - w' = fma(+-MU, v, w) bit-identical to w + (MU*sign)*v (MU=2^-10 exact).
//  - stores UNCLIPPED d; finalize applies the clamp.
// ---------------------------------------------------------------------------
__global__ __launch_bounds__(64, 1) void scan_kernel(const float4* __restrict__ tmp4,
                                                     const float* __restrict__ w0g,
                                                     float* __restrict__ dT) {
    __shared__ float4 lds[NBUF * TILE * 64];  // 64 KB ring

    const int lane = threadIdx.x;
    const int z = blockIdx.x * 64 + lane;
    if (z >= ZB) return;  // single wave per block: no barriers, early-out safe

    float w0 = w0g[z * 3 + 0];
    float w1 = w0g[z * 3 + 1];
    float w2 = w0g[z * 3 + 2];

    const float4* gsrc = tmp4 + z;  // 64 lanes -> contiguous 1KB per step
    float* outp = dT + z;

    auto stage = [&](int tile) {
        const float4* gp = gsrc + (size_t)tile * (TILE * ZB);
        float4* lp = &lds[(tile & (NBUF - 1)) * (TILE * 64)];  // wave-uniform base
#pragma unroll
        for (int k = 0; k < TILE; ++k) GL_LDS16(gp + (size_t)k * ZB, lp + k * 64);
    };

    float4 ra[TILE], rb[TILE];

#define READTILE(dst, tile_)                                                   \
    {                                                                          \
        const float4* lb = &lds[((tile_) & (NBUF - 1)) * (TILE * 64)] + lane;  \
        _Pragma("unroll") for (int k = 0; k < TILE; ++k) dst[k] = lb[k * 64];  \
        __builtin_amdgcn_sched_barrier(0); /* pin reads before compute */      \
    }

#define COMPUTE(buf, tile_)                                                    \
    {                                                                          \
        float* op = outp + (size_t)(tile_) * (TILE * ZB);                      \
        _Pragma("unroll") for (int i = 0; i < TILE; ++i) {                     \
            const float4 v = buf[i];                                           \
            float d = __fadd_rn(                                               \
                __fadd_rn(__fmul_rn(w0, v.z), __fmul_rn(w1, v.y)),             \
                __fmul_rn(w2, v.x));                                           \
            float sg = (v.w > d) ? kMU() : ((v.w < d) ? -kMU() : 0.0f);        \
            w0 = __builtin_fmaf(sg, v.z, w0);                                  \
            w1 = __builtin_fmaf(sg, v.y, w1);                                  \
            w2 = __builtin_fmaf(sg, v.x, w2);                                  \
            op[(size_t)i * ZB] = d;                                            \
        }                                                                      \
    }

    // prologue: 3 tiles in flight, tile 0 into registers
    stage(0);
    stage(1);
    stage(2);
    asm volatile("s_waitcnt vmcnt(32)" ::: "memory");  // 32 ops after L(0)
    READTILE(ra, 0);

    // startup pair peeled (queue not yet in steady state)
    stage(3);
    asm volatile("s_waitcnt vmcnt(32)" ::: "memory");  // L(2),L(3) after L(1)
    READTILE(rb, 1);
    COMPUTE(ra, 0);
    stage(4);
    asm volatile("s_waitcnt vmcnt(48)" ::: "memory");  // L(3),S(0),L(4) after L(2)
    READTILE(ra, 2);
    COMPUTE(rb, 1);

    // steady state: 64 vmem ops issued after tile (tp+1)'s / (tp+2)'s loads
    for (int tp = 2; tp < NT - 4; tp += 2) {
        stage(tp + 3);
        asm volatile("s_waitcnt vmcnt(48)" ::: "memory");
        READTILE(rb, tp + 1);
        COMPUTE(ra, tp);
        stage(tp + 4);
        asm volatile("s_waitcnt vmcnt(48)" ::: "memory");
        READTILE(ra, tp + 2);
        COMPUTE(rb, tp + 1);
    }
    // computed tiles 0..NT-5; ra holds tile NT-4; tiles through NT-2 staged

    // tail: 4 tiles, single full drain
    stage(NT - 1);
    asm volatile("s_waitcnt vmcnt(0)" ::: "memory");
    READTILE(rb, NT - 3);
    COMPUTE(ra, NT - 4);
    READTILE(ra, NT - 2);
    COMPUTE(rb, NT - 3);
    READTILE(rb, NT - 1);
    COMPUTE(ra, NT - 2);
    COMPUTE(rb, NT - 1);

#undef READTILE
#undef COMPUTE
}

// ---------------------------------------------------------------------------
// Phase C: elementwise outputs from dT + image. (unchanged, verified)
// ---------------------------------------------------------------------------
__global__ __launch_bounds__(256) void finalize_kernel(const float* __restrict__ img,
                                                       const float* __restrict__ dT,
                                                       float* __restrict__ out) {
    __shared__ float lds[64 * ZB];  // 51.7 KB
    const int t0 = blockIdx.x * 64;
    const float* src = dT + (size_t)t0 * ZB;
    for (int i = threadIdx.x; i < 64 * ZB; i += 256) lds[i] = src[i];
    __syncthreads();

    for (int k = 0; k < 51; ++k) {
        int e = k * 256 + threadIdx.x;
        if (e < 64 * ZB) {
            int zz = e >> 6;
            int tl = e & 63;
            float dv = lds[tl * ZB + zz];            // stride 202 -> 2-way bank alias (free)
            float pred = fminf(fmaxf(dv, MINV), MAXV);
            size_t o = (size_t)zz * YX + t0 + tl;
            float s = img[o];
            float res = __fsub_rn(s, pred);
            int q = (int)rintf(res);                  // round-half-even == jnp.round
            int m = (q >= 0) ? (2 * q) : (-2 * q - 1);
            out[o] = pred;                            // predictions
            out[NTOT + o] = res;                      // residuals
            out[2 * NTOT + o] = res;                  // quantized_residuals
            out[3 * NTOT + o] = (float)m;             // mapped_indices
            out[5 * NTOT + o] = __fadd_rn(pred, res); // reconstructed
        }
    }
}

// ---------------------------------------------------------------------------
// Phase D: sample_representatives = image. (unchanged)
// ---------------------------------------------------------------------------
__global__ __launch_bounds__(256) void repr_kernel(const float4* __restrict__ img4,
                                                   float4* __restrict__ out4) {
    size_t n4 = NTOT / 4;
    for (size_t i = (size_t)blockIdx.x * blockDim.x + threadIdx.x; i < n4;
         i += (size_t)gridDim.x * blockDim.x)
        out4[i] = img4[i];
}

extern "C" void kernel_launch(void* const* d_in, const int* in_sizes, int n_in,
                              void* d_out, int out_size, void* d_ws, size_t ws_size,
                              hipStream_t stream) {
    const float* img = (const float*)d_in[0];
    const float* w0g = (const float*)d_in[1];
    float* out = (float*)d_out;

    // Scratch carved out of d_out (dead before the final writers touch it):
    //   tmp4 = d_out[0 .. 4N) floats  (exactly N float4s)
    //   dT   = d_out[4N .. 5N) floats (later overwritten by repr_kernel)
    float4* tmp4 = (float4*)d_out;
    float* dT = out + 4 * NTOT;

    dim3 gA(YX / 64, 4);
    pack_kernel<<<gA, 256, 0, stream>>>(img, tmp4);
    scan_kernel<<<4, 64, 0, stream>>>(tmp4, w0g, dT);
    finalize_kernel<<<YX / 64, 256, 0, stream>>>(img, dT, out);
    repr_kernel<<<4096, 256, 0, stream>>>((const float4*)img, (float4*)(out + 4 * NTOT));
}

// Round 3
// 4329.063 us; speedup vs baseline: 1.2664x; 1.0267x over previous
//
#include <hip/hip_runtime.h>

#define ZB 202
#define ZBP 208            // imgT row stride (floats): [0,1,2]=zeros(bands -3..-1), 3+z=band z
#define YX 65536
#define NTOT ((size_t)ZB * YX)

#define TILE 16            // pixels per LDS tile (256 B/step: 64 lanes x 4B)
#define NT (YX / TILE)     // 4096 tiles
#define NBUF 4             // LDS ring buffers
#define PAD 4              // front slack so feeder lanes' (lane-3) reads stay in-bounds

__device__ __forceinline__ constexpr float kMU() { return 0.0009765625f; }  // 2^-10
#define MINV (-32768.0f)
#define MAXV (32767.0f)

// global->LDS direct DMA, dword wide: per-lane gaddr, LDS dest = uniform base + lane*4
#define GL_LDS4(g, l)                                                     \
    __builtin_amdgcn_global_load_lds(                                     \
        (const __attribute__((address_space(1))) void*)(g),               \
        (__attribute__((address_space(3))) void*)(l), 4, 0, 0)

// ---------------------------------------------------------------------------
// Phase A: transpose img[z][t] -> imgT[t*ZBP + 3 + z], with imgT[t*ZBP+{0,1,2}]=0
// (zero-padded bands -3..-1) and tail offsets 205..207 zeroed.  Replaces the
// old 212 MB tmp4 pack with a 54 MB pixel-major copy: scan now needs only
// 4 B/lane/step because band neighbors are adjacent lanes' values.
// ---------------------------------------------------------------------------
__global__ __launch_bounds__(256) void tr_kernel(const float* __restrict__ img,
                                                 float* __restrict__ imgT) {
    __shared__ float lds[64 * 65];
    const int t0 = blockIdx.x * 64;
    const int zi = blockIdx.y;           // 0..3
    const int zw0 = zi * 64 - 3;         // window band base (offset zi*64 <-> band zw0)
    const int tid = threadIdx.x;
    const int c = tid & 63;
    const int r0 = tid >> 6;

    for (int k = 0; k < 16; ++k) {
        int rr = r0 * 16 + k;            // z-window row
        int z = zw0 + rr;
        float v = 0.0f;
        if (z >= 0 && z < ZB) v = img[(size_t)z * YX + t0 + c];  // coalesced along t
        lds[rr * 65 + c] = v;
    }
    __syncthreads();

    const int l = tid & 63;
    const int off = zi * 64 + l;         // imgT row offset
    if (off < ZBP) {                     // zi==3: only l<16
        for (int k = 0; k < 16; ++k) {
            int tr = r0 * 16 + k;
            imgT[(size_t)(t0 + tr) * ZBP + off] = lds[l * 65 + tr];  // coalesced along z
        }
    }
}

// ---------------------------------------------------------------------------
// Phase B: sequential sign-LMS scan. One wave per block, 4 blocks.
//
// Round-2 post-mortem: per-wave global-load throughput (~7-10 B/cyc) was the
// wall; 16 B/lane/step of pre-packed neighbors = 150+ cyc/step no matter how
// the LDS/register pipeline is arranged.  This version loads 4 B/lane/step:
//   - block b's lanes cover bands 61b-3 .. 61b+60 (lanes 0-2 = feeders;
//     windows overlap 3; block 0's feeders read the stored zeros).
//   - stage: ONE dword/lane/step via global_load_lds (coalesced 256 B).
//   - neighbors {n0,n1,n2} = LDS row positions lane-1..lane-3 (4x ds_read_b32,
//     consecutive addrs -> 2-way bank alias = free).
// Pipeline skeleton (vmcnt counts: 16 loads + 16 stores per tile, steady-state
// wait vmcnt(48), startup 32/48, vmcnt(0) only in the tail) is byte-for-byte
// the round-2-verified structure; ra/rb register tile buffers with pinned
// batch ds_reads one tile ahead.
//
// Recurrence kept bit-exact vs the verified kernel:
//  - identical float values reach identical ops in identical order
//    (imgT is a bit-copy; zero neighbors come from stored zeros).
//  - d: same 3-mul + left-to-right 2-add order; sign(s-clip(d))==sign(s-d);
//    w' = fma(+-MU, v, w); stores UNCLIPPED d (finalize clamps).
// ---------------------------------------------------------------------------
__global__ __launch_bounds__(64, 1) void scan_kernel(const float* __restrict__ imgT,
                                                     const float* __restrict__ w0g,
                                                     float* __restrict__ dT) {
    __shared__ float ldsf[PAD + NBUF * TILE * 64];  // 16.4 KB

    const int lane = threadIdx.x;
    const int b = blockIdx.x;                 // 0..3
    const int band = 61 * b + lane - 3;       // this lane's band (feeders: <61b or junk)
    const int goff = 61 * b + lane;           // imgT row offset to load (0..246)
    const bool do_store = (lane >= 3) && (band < ZB);
    const int wband = band < 0 ? 0 : (band > ZB - 1 ? ZB - 1 : band);

    float w0 = w0g[wband * 3 + 0];
    float w1 = w0g[wband * 3 + 1];
    float w2 = w0g[wband * 3 + 2];

    const float* gsrc = imgT + goff;          // +t*ZBP per step; 64 lanes contiguous
    float* outp = dT + wband;                 // dT[t][z] layout, stride ZB (finalize's)

    auto stage = [&](int tile) {
        const float* gp = gsrc + (size_t)tile * (TILE * ZBP);
        float* lp = ldsf + PAD + (tile & (NBUF - 1)) * (TILE * 64);  // wave-uniform
#pragma unroll
        for (int k = 0; k < TILE; ++k) GL_LDS4(gp + (size_t)k * ZBP, lp + k * 64);
    };

    float4 ra[TILE], rb[TILE];

    // dst[k] = {n2,n1,n0,s} = LDS row positions {lane-3,lane-2,lane-1,lane};
    // row content j = band 61b+j-3, so this matches the old tmp4 component map.
#define READTILE(dst, tile_)                                                   \
    {                                                                          \
        const int lb = PAD + ((tile_) & (NBUF - 1)) * (TILE * 64) + lane;      \
        _Pragma("unroll") for (int k = 0; k < TILE; ++k) {                     \
            dst[k].x = ldsf[lb + k * 64 - 3];                                  \
            dst[k].y = ldsf[lb + k * 64 - 2];                                  \
            dst[k].z = ldsf[lb + k * 64 - 1];                                  \
            dst[k].w = ldsf[lb + k * 64 - 0];                                  \
        }                                                                      \
        __builtin_amdgcn_sched_barrier(0); /* pin reads before compute */      \
    }

#define COMPUTE(buf, tile_)                                                    \
    {                                                                          \
        float* op = outp + (size_t)(tile_) * (TILE * ZB);                      \
        _Pragma("unroll") for (int i = 0; i < TILE; ++i) {                     \
            const float4 v = buf[i];                                           \
            float d = __fadd_rn(                                               \
                __fadd_rn(__fmul_rn(w0, v.z), __fmul_rn(w1, v.y)),             \
                __fmul_rn(w2, v.x));                                           \
            float sg = (v.w > d) ? kMU() : ((v.w < d) ? -kMU() : 0.0f);        \
            w0 = __builtin_fmaf(sg, v.z, w0);                                  \
            w1 = __builtin_fmaf(sg, v.y, w1);                                  \
            w2 = __builtin_fmaf(sg, v.x, w2);                                  \
            if (do_store) op[(size_t)i * ZB] = d;                              \
        }                                                                      \
    }

    // prologue: 3 tiles in flight, tile 0 into registers
    stage(0);
    stage(1);
    stage(2);
    asm volatile("s_waitcnt vmcnt(32)" ::: "memory");  // 32 ops after L(0)
    READTILE(ra, 0);

    // startup pair peeled (queue not yet in steady state)
    stage(3);
    asm volatile("s_waitcnt vmcnt(32)" ::: "memory");  // L(2),L(3) after L(1)
    READTILE(rb, 1);
    COMPUTE(ra, 0);
    stage(4);
    asm volatile("s_waitcnt vmcnt(48)" ::: "memory");  // L(3),S(0),L(4) after L(2)
    READTILE(ra, 2);
    COMPUTE(rb, 1);

    // steady state: 64 vmem ops issued after the tile we're about to read
    for (int tp = 2; tp < NT - 4; tp += 2) {
        stage(tp + 3);
        asm volatile("s_waitcnt vmcnt(48)" ::: "memory");
        READTILE(rb, tp + 1);
        COMPUTE(ra, tp);
        stage(tp + 4);
        asm volatile("s_waitcnt vmcnt(48)" ::: "memory");
        READTILE(ra, tp + 2);
        COMPUTE(rb, tp + 1);
    }
    // computed tiles 0..NT-5; ra holds tile NT-4; tiles through NT-2 staged

    // tail: 4 tiles, single full drain
    stage(NT - 1);
    asm volatile("s_waitcnt vmcnt(0)" ::: "memory");
    READTILE(rb, NT - 3);
    COMPUTE(ra, NT - 4);
    READTILE(ra, NT - 2);
    COMPUTE(rb, NT - 3);
    READTILE(rb, NT - 1);
    COMPUTE(ra, NT - 2);
    COMPUTE(rb, NT - 1);

#undef READTILE
#undef COMPUTE
}

// ---------------------------------------------------------------------------
// Phase C: elementwise outputs from dT + image. (unchanged, verified)
// ---------------------------------------------------------------------------
__global__ __launch_bounds__(256) void finalize_kernel(const float* __restrict__ img,
                                                       const float* __restrict__ dT,
                                                       float* __restrict__ out) {
    __shared__ float lds[64 * ZB];  // 51.7 KB
    const int t0 = blockIdx.x * 64;
    const float* src = dT + (size_t)t0 * ZB;
    for (int i = threadIdx.x; i < 64 * ZB; i += 256) lds[i] = src[i];
    __syncthreads();

    for (int k = 0; k < 51; ++k) {
        int e = k * 256 + threadIdx.x;
        if (e < 64 * ZB) {
            int zz = e >> 6;
            int tl = e & 63;
            float dv = lds[tl * ZB + zz];            // stride 202 -> 2-way bank alias (free)
            float pred = fminf(fmaxf(dv, MINV), MAXV);
            size_t o = (size_t)zz * YX + t0 + tl;
            float s = img[o];
            float res = __fsub_rn(s, pred);
            int q = (int)rintf(res);                  // round-half-even == jnp.round
            int m = (q >= 0) ? (2 * q) : (-2 * q - 1);
            out[o] = pred;                            // predictions
            out[NTOT + o] = res;                      // residuals
            out[2 * NTOT + o] = res;                  // quantized_residuals
            out[3 * NTOT + o] = (float)m;             // mapped_indices
            out[5 * NTOT + o] = __fadd_rn(pred, res); // reconstructed
        }
    }
}

// ---------------------------------------------------------------------------
// Phase D: sample_representatives = image. (unchanged)
// ---------------------------------------------------------------------------
__global__ __launch_bounds__(256) void repr_kernel(const float4* __restrict__ img4,
                                                   float4* __restrict__ out4) {
    size_t n4 = NTOT / 4;
    for (size_t i = (size_t)blockIdx.x * blockDim.x + threadIdx.x; i < n4;
         i += (size_t)gridDim.x * blockDim.x)
        out4[i] = img4[i];
}

extern "C" void kernel_launch(void* const* d_in, const int* in_sizes, int n_in,
                              void* d_out, int out_size, void* d_ws, size_t ws_size,
                              hipStream_t stream) {
    const float* img = (const float*)d_in[0];
    const float* w0g = (const float*)d_in[1];
    float* out = (float*)d_out;

    // Scratch carved out of d_out (dead before the final writers touch it):
    //   imgT = out[0 .. YX*ZBP+64) floats (13.6M floats = 54.5 MB << 4N;
    //          block 3's tail lanes read up to +246 past the last row: the
    //          +64 slack keeps those junk reads in-bounds)
    //   dT   = out[4N .. 5N) floats (later overwritten by repr_kernel)
    float* imgT = out;
    float* dT = out + 4 * NTOT;

    tr_kernel<<<dim3(YX / 64, 4), 256, 0, stream>>>(img, imgT);
    scan_kernel<<<4, 64, 0, stream>>>(imgT, w0g, dT);
    finalize_kernel<<<YX / 64, 256, 0, stream>>>(img, dT, out);
    repr_kernel<<<4096, 256, 0, stream>>>((const float4*)img, (float4*)(out + 4 * NTOT));
}